// Round 1
// baseline (1513.431 us; speedup 1.0000x reference)
//
#include <hip/hip_runtime.h>
#include <hip/hip_bf16.h>
#include <cstdint>

// Problem: out = softmax((A@J + B) * (1/sqrt(S)) + mask) @ P
// A,J,B,P: [64][1024][1024] fp32;  mask: [1024][1024] fp32;  out fp32.
// Staged bf16-MFMA implementation (m97-style GEMM structure).

typedef __bf16 bf16x8 __attribute__((ext_vector_type(8)));
typedef __bf16 bf16x4 __attribute__((ext_vector_type(4)));
typedef float f32x4 __attribute__((ext_vector_type(4)));

static constexpr int SS = 1024;        // sequence length
static constexpr int BH = 64;          // batch*heads
static constexpr size_t SLICE = (size_t)SS * SS;   // elems per bh slice

// ---- async global->LDS, 16B per lane (verified m97 pattern) ----
__device__ __forceinline__ void async16(void* lds, const void* g) {
    __builtin_amdgcn_global_load_lds(
        (__attribute__((address_space(1))) void*)(g),
        (__attribute__((address_space(3))) void*)(lds), 16, 0, 0);
}

// ---- kernel 1: elementwise fp32 -> bf16 cast (A) ----
__global__ __launch_bounds__(256) void cast_bf16(const float4* __restrict__ in,
                                                 bf16x4* __restrict__ out, int n4) {
    int i = blockIdx.x * 256 + threadIdx.x;
    if (i < n4) {
        float4 v = in[i];
        bf16x4 o = {(__bf16)v.x, (__bf16)v.y, (__bf16)v.z, (__bf16)v.w};
        out[i] = o;
    }
}

// ---- kernel 2: 32x32 tiled transpose + cast: out[bh][c][r] = (bf16)in[bh][r][c] ----
__global__ __launch_bounds__(256) void transpose_cast(const float* __restrict__ in,
                                                      __bf16* __restrict__ out) {
    __shared__ float tile[32][33];
    const int bh = blockIdx.z;
    const int r0 = blockIdx.y * 32, c0 = blockIdx.x * 32;
    const int t = threadIdx.x;
    const int tr = t >> 3, tc4 = (t & 7) * 4;
    const float4 v = *(const float4*)(in + (size_t)bh * SLICE + (size_t)(r0 + tr) * SS + c0 + tc4);
    tile[tr][tc4 + 0] = v.x;
    tile[tr][tc4 + 1] = v.y;
    tile[tr][tc4 + 2] = v.z;
    tile[tr][tc4 + 3] = v.w;
    __syncthreads();
    const int oc = t >> 3;           // column (becomes output row)
    const int orr = (t & 7) * 4;     // 4 consecutive original rows (output cols)
    bf16x4 o = {(__bf16)tile[orr + 0][oc], (__bf16)tile[orr + 1][oc],
                (__bf16)tile[orr + 2][oc], (__bf16)tile[orr + 3][oc]};
    *(bf16x4*)(out + (size_t)bh * SLICE + (size_t)(c0 + oc) * SS + r0 + orr) = o;
}

// ---- GEMM core: C[i][j] = sum_k Aop[bh][i][k] * Bop[bh][j][k] (both bf16, K-contig) ----
// 128x128 block tile, BK=32, 256 threads = 4 waves in 2x2, each wave 64x64 (4x4 MFMA tiles).

// kernel 3: scores = (A@J + B) * scale + mask (fp32 out)
__global__ __launch_bounds__(256) void gemm_scores(const __bf16* __restrict__ Ab,
                                                   const __bf16* __restrict__ Jt,
                                                   const float* __restrict__ Bm,
                                                   const float* __restrict__ mask,
                                                   float* __restrict__ scores) {
    __shared__ __align__(16) __bf16 As[128 * 32];
    __shared__ __align__(16) __bf16 Bs[128 * 32];
    const int tid = threadIdx.x, lane = tid & 63, w = tid >> 6;
    const int wm = w >> 1, wn = w & 1;
    const int l16 = lane & 15, l4 = lane >> 4;
    const int bh = blockIdx.z;
    const int i0 = blockIdx.y * 128, j0 = blockIdx.x * 128;
    const size_t bhoff = (size_t)bh * SLICE;

    const __bf16* Ag = Ab + bhoff + (size_t)(i0 + w * 32 + (lane >> 2)) * SS + (lane & 3) * 8;
    const __bf16* Bg = Jt + bhoff + (size_t)(j0 + w * 32 + (lane >> 2)) * SS + (lane & 3) * 8;
    char* lA0 = (char*)As + w * 2048 + lane * 16;
    char* lB0 = (char*)Bs + w * 2048 + lane * 16;
    const __bf16* ar = As + (wm * 64 + l16) * 32 + l4 * 8;
    const __bf16* br = Bs + (wn * 64 + l16) * 32 + l4 * 8;

    f32x4 acc[4][4] = {};
    for (int kt = 0; kt < SS / 32; ++kt) {
        async16(lA0, Ag); async16(lA0 + 1024, Ag + 16 * SS);
        async16(lB0, Bg); async16(lB0 + 1024, Bg + 16 * SS);
        Ag += 32; Bg += 32;
        __syncthreads();
        bf16x8 af[4], bfr[4];
#pragma unroll
        for (int mi = 0; mi < 4; ++mi) af[mi] = *(const bf16x8*)(ar + mi * 16 * 32);
#pragma unroll
        for (int ni = 0; ni < 4; ++ni) bfr[ni] = *(const bf16x8*)(br + ni * 16 * 32);
#pragma unroll
        for (int mi = 0; mi < 4; ++mi)
#pragma unroll
            for (int ni = 0; ni < 4; ++ni)
                acc[mi][ni] = __builtin_amdgcn_mfma_f32_16x16x32_bf16(af[mi], bfr[ni], acc[mi][ni], 0, 0, 0);
        __syncthreads();
    }
    const float sc = 0.03125f;  // 1/sqrt(1024)
#pragma unroll
    for (int mi = 0; mi < 4; ++mi) {
#pragma unroll
        for (int r = 0; r < 4; ++r) {
            const int ig = i0 + wm * 64 + mi * 16 + l4 * 4 + r;
#pragma unroll
            for (int ni = 0; ni < 4; ++ni) {
                const int jg = j0 + wn * 64 + ni * 16 + l16;
                const size_t off = bhoff + (size_t)ig * SS + jg;
                scores[off] = (acc[mi][ni][r] + Bm[off]) * sc + mask[(size_t)ig * SS + jg];
            }
        }
    }
}

// kernel 5: out = attn @ P (plain fp32 store)
__global__ __launch_bounds__(256) void gemm_out(const __bf16* __restrict__ At,
                                                const __bf16* __restrict__ Pt,
                                                float* __restrict__ out) {
    __shared__ __align__(16) __bf16 As[128 * 32];
    __shared__ __align__(16) __bf16 Bs[128 * 32];
    const int tid = threadIdx.x, lane = tid & 63, w = tid >> 6;
    const int wm = w >> 1, wn = w & 1;
    const int l16 = lane & 15, l4 = lane >> 4;
    const int bh = blockIdx.z;
    const int i0 = blockIdx.y * 128, j0 = blockIdx.x * 128;
    const size_t bhoff = (size_t)bh * SLICE;

    const __bf16* Ag = At + bhoff + (size_t)(i0 + w * 32 + (lane >> 2)) * SS + (lane & 3) * 8;
    const __bf16* Bg = Pt + bhoff + (size_t)(j0 + w * 32 + (lane >> 2)) * SS + (lane & 3) * 8;
    char* lA0 = (char*)As + w * 2048 + lane * 16;
    char* lB0 = (char*)Bs + w * 2048 + lane * 16;
    const __bf16* ar = As + (wm * 64 + l16) * 32 + l4 * 8;
    const __bf16* br = Bs + (wn * 64 + l16) * 32 + l4 * 8;

    f32x4 acc[4][4] = {};
    for (int kt = 0; kt < SS / 32; ++kt) {
        async16(lA0, Ag); async16(lA0 + 1024, Ag + 16 * SS);
        async16(lB0, Bg); async16(lB0 + 1024, Bg + 16 * SS);
        Ag += 32; Bg += 32;
        __syncthreads();
        bf16x8 af[4], bfr[4];
#pragma unroll
        for (int mi = 0; mi < 4; ++mi) af[mi] = *(const bf16x8*)(ar + mi * 16 * 32);
#pragma unroll
        for (int ni = 0; ni < 4; ++ni) bfr[ni] = *(const bf16x8*)(br + ni * 16 * 32);
#pragma unroll
        for (int mi = 0; mi < 4; ++mi)
#pragma unroll
            for (int ni = 0; ni < 4; ++ni)
                acc[mi][ni] = __builtin_amdgcn_mfma_f32_16x16x32_bf16(af[mi], bfr[ni], acc[mi][ni], 0, 0, 0);
        __syncthreads();
    }
#pragma unroll
    for (int mi = 0; mi < 4; ++mi) {
#pragma unroll
        for (int r = 0; r < 4; ++r) {
            const int ig = i0 + wm * 64 + mi * 16 + l4 * 4 + r;
#pragma unroll
            for (int ni = 0; ni < 4; ++ni) {
                const int jg = j0 + wn * 64 + ni * 16 + l16;
                out[bhoff + (size_t)ig * SS + jg] = acc[mi][ni][r];
            }
        }
    }
}

// ---- kernel 4: row softmax, fp32 scores -> bf16 attn ----
__global__ __launch_bounds__(256) void softmax_rows(const float* __restrict__ scores,
                                                    __bf16* __restrict__ attn) {
    const size_t row = blockIdx.x;          // bh*1024 + i, 0..65535
    const int t = threadIdx.x;
    const int lane = t & 63, w = t >> 6;
    __shared__ float red[8];

    float4 v = *(const float4*)(scores + row * SS + t * 4);
    float m = fmaxf(fmaxf(v.x, v.y), fmaxf(v.z, v.w));
#pragma unroll
    for (int o = 32; o; o >>= 1) m = fmaxf(m, __shfl_down(m, o));
    if (lane == 0) red[w] = m;
    __syncthreads();
    const float bm = fmaxf(fmaxf(red[0], red[1]), fmaxf(red[2], red[3]));
    const float e0 = __expf(v.x - bm), e1 = __expf(v.y - bm);
    const float e2 = __expf(v.z - bm), e3 = __expf(v.w - bm);
    float s = e0 + e1 + e2 + e3;
#pragma unroll
    for (int o = 32; o; o >>= 1) s += __shfl_down(s, o);
    __syncthreads();
    if (lane == 0) red[4 + w] = s;
    __syncthreads();
    const float inv = 1.0f / (red[4] + red[5] + red[6] + red[7]);
    bf16x4 o = {(__bf16)(e0 * inv), (__bf16)(e1 * inv), (__bf16)(e2 * inv), (__bf16)(e3 * inv)};
    *(bf16x4*)(attn + row * SS + t * 4) = o;
}

extern "C" void kernel_launch(void* const* d_in, const int* in_sizes, int n_in,
                              void* d_out, int out_size, void* d_ws, size_t ws_size,
                              hipStream_t stream) {
    const float* A    = (const float*)d_in[0];
    const float* J    = (const float*)d_in[1];
    const float* Bm   = (const float*)d_in[2];
    const float* P    = (const float*)d_in[3];
    const float* mask = (const float*)d_in[4];
    float* out = (float*)d_out;

    char* ws = (char*)d_ws;
    const size_t MB128 = (size_t)128 * 1024 * 1024;
    __bf16* Ab   = (__bf16*)ws;                    // 128 MiB; reused as attn after gemm_scores
    __bf16* Jt   = (__bf16*)(ws + MB128);          // 128 MiB
    __bf16* Pt   = (__bf16*)(ws + 2 * MB128);      // 128 MiB
    float*  scr  = (float*)(ws + 3 * MB128);       // 256 MiB fp32 scores
    __bf16* attn = Ab;                             // alias: Ab is dead after gemm_scores

    const int n4 = (int)(BH * SLICE / 4);          // 16777216 float4 groups
    cast_bf16<<<dim3(n4 / 256), dim3(256), 0, stream>>>((const float4*)A, (bf16x4*)Ab, n4);
    transpose_cast<<<dim3(32, 32, BH), dim3(256), 0, stream>>>(J, Jt);
    transpose_cast<<<dim3(32, 32, BH), dim3(256), 0, stream>>>(P, Pt);
    gemm_scores<<<dim3(8, 8, BH), dim3(256), 0, stream>>>(Ab, Jt, Bm, mask, scr);
    softmax_rows<<<dim3(BH * SS), dim3(256), 0, stream>>>(scr, attn);
    gemm_out<<<dim3(8, 8, BH), dim3(256), 0, stream>>>(attn, Pt, out);
}